// Round 1
// baseline (440.595 us; speedup 1.0000x reference)
//
#include <hip/hip_runtime.h>

typedef float f32x4 __attribute__((ext_vector_type(4)));
typedef __bf16 bf16x8 __attribute__((ext_vector_type(8)));
typedef unsigned short u16x8 __attribute__((ext_vector_type(8)));

#define DEV static __device__ __forceinline__

DEV float bf2f(unsigned short h) {
  unsigned int u = ((unsigned int)h) << 16;
  return __builtin_bit_cast(float, u);
}
DEV unsigned short f2bf(float f) {
  unsigned int u = __builtin_bit_cast(unsigned int, f);
  u += 0x7fff + ((u >> 16) & 1);   // RTNE
  return (unsigned short)(u >> 16);
}

DEV void g2l16(const void* g, void* l) {
  __builtin_amdgcn_global_load_lds(
      (const __attribute__((address_space(1))) void*)g,
      (__attribute__((address_space(3))) void*)l, 16, 0, 0);
}

// ---------------- fp32 -> bf16 convert (n % 8 == 0) ----------------
__global__ __launch_bounds__(256) void k_cvt(const float* __restrict__ in,
                                             unsigned short* __restrict__ out, int n) {
  int i = (blockIdx.x * 256 + threadIdx.x) * 8;
  if (i >= n) return;
  float4 a = *(const float4*)(in + i);
  float4 b = *(const float4*)(in + i + 4);
  u16x8 r;
  r[0] = f2bf(a.x); r[1] = f2bf(a.y); r[2] = f2bf(a.z); r[3] = f2bf(a.w);
  r[4] = f2bf(b.x); r[5] = f2bf(b.y); r[6] = f2bf(b.z); r[7] = f2bf(b.w);
  *(u16x8*)(out + i) = r;
}

// ---------------- NT GEMM: C[M,N] = A[M,K] * B[N,K]^T  (m97 structure) ----------------
// 128x128 tile, BK=64, 4 waves (2x2), global_load_lds + T2 XOR swizzle via pre-swizzled source.
template <typename OUT>
__global__ __launch_bounds__(256) void k_gemm_bt(const unsigned short* __restrict__ A,
                                                 const unsigned short* __restrict__ B,
                                                 OUT* __restrict__ C, int M, int N, int K) {
  __shared__ unsigned short As[128 * 64];
  __shared__ unsigned short Bs[128 * 64];
  const int tid = threadIdx.x;
  const int wid = tid >> 6, lane = tid & 63;
  const int g = lane >> 4, r16 = lane & 15;
  const int m0 = blockIdx.x * 128, n0 = blockIdx.y * 128;
  const int wr = wid >> 1, wc = wid & 1;

  f32x4 acc[4][4];
#pragma unroll
  for (int i = 0; i < 4; ++i)
#pragma unroll
    for (int j = 0; j < 4; ++j) acc[i][j] = f32x4{0.f, 0.f, 0.f, 0.f};

  const int cb = (lane & 7) * 16;  // column byte within 128B row (staging)

  for (int k0 = 0; k0 < K; k0 += 64) {
#pragma unroll
    for (int c = 0; c < 4; ++c) {
      int i = wid * 4 + c;               // chunk 0..15, 1KB each (8 rows)
      int row = i * 8 + (lane >> 3);
      int sc = cb ^ ((row & 7) << 4);    // pre-swizzled source column
      g2l16((const char*)A + ((size_t)(m0 + row) * K + k0) * 2 + sc, (char*)As + i * 1024);
      g2l16((const char*)B + ((size_t)(n0 + row) * K + k0) * 2 + sc, (char*)Bs + i * 1024);
    }
    __syncthreads();
#pragma unroll
    for (int kh = 0; kh < 2; ++kh) {
      bf16x8 af[4], bfr[4];
#pragma unroll
      for (int m = 0; m < 4; ++m) {
        int row = wr * 64 + m * 16 + r16;
        int byte = row * 128 + ((g * 16 + kh * 64) ^ ((row & 7) << 4));
        af[m] = *(const bf16x8*)((const char*)As + byte);
      }
#pragma unroll
      for (int n = 0; n < 4; ++n) {
        int row = wc * 64 + n * 16 + r16;
        int byte = row * 128 + ((g * 16 + kh * 64) ^ ((row & 7) << 4));
        bfr[n] = *(const bf16x8*)((const char*)Bs + byte);
      }
#pragma unroll
      for (int m = 0; m < 4; ++m)
#pragma unroll
        for (int n = 0; n < 4; ++n)
          acc[m][n] = __builtin_amdgcn_mfma_f32_16x16x32_bf16(af[m], bfr[n], acc[m][n], 0, 0, 0);
    }
    __syncthreads();
  }
  // epilogue: C/D layout col=lane&15, row=(lane>>4)*4+j
#pragma unroll
  for (int m = 0; m < 4; ++m)
#pragma unroll
    for (int n = 0; n < 4; ++n)
#pragma unroll
      for (int j = 0; j < 4; ++j) {
        int row = m0 + wr * 64 + m * 16 + g * 4 + j;
        int col = n0 + wc * 64 + n * 16 + r16;
        float v = acc[m][n][j];
        if constexpr (sizeof(OUT) == 2)
          C[(size_t)row * N + col] = f2bf(v);
        else
          C[(size_t)row * N + col] = v;
      }
}

// ---------------- RMSNorm + RoPE + q_gain epilogue ----------------
// qkv layout: [B*S][1536] bf16 (q 0..1023, k 1024..1279, v 1280..1535)
// writes qn [B*S][1024], kn [B*S][256] (v untouched; attention reads it from qkv)
__global__ __launch_bounds__(256) void k_normrope(const unsigned short* __restrict__ qkv,
                                                  const float* __restrict__ qg,
                                                  unsigned short* __restrict__ qn,
                                                  unsigned short* __restrict__ kn) {
  const int wid = threadIdx.x >> 6, lane = threadIdx.x & 63;
  const int b = blockIdx.x >> 7;            // 128 blocks per batch (16 tokens each)
  const int s0 = (blockIdx.x & 127) * 16;
  const int dh = lane & 31;
  const float inv_freq = powf(10000.0f, -(float)dh * (1.0f / 32.0f));
  for (int t = 0; t < 16; ++t) {
    const int s = s0 + t;
    float sn, cs;
    sincosf((float)s * inv_freq, &sn, &cs);
    const size_t base = (size_t)(b * 2048 + s) * 1536;
#pragma unroll
    for (int u = 0; u < 5; ++u) {
      const int unit = wid * 5 + u;  // 0..15 = q heads, 16..19 = k heads
      const int col = (unit < 16) ? unit * 64 : 1024 + (unit - 16) * 64;
      float v = bf2f(qkv[base + col + lane]);
      float ss = v * v;
      ss += __shfl_xor(ss, 1);  ss += __shfl_xor(ss, 2);  ss += __shfl_xor(ss, 4);
      ss += __shfl_xor(ss, 8);  ss += __shfl_xor(ss, 16); ss += __shfl_xor(ss, 32);
      float xr = v * rsqrtf(ss * (1.0f / 64.0f) + 1e-6f);
      float xp = __shfl_xor(xr, 32);
      // half-split RoPE: d<32: t1*cos + t2*sin ; d>=32: -t1*sin + t2*cos
      float o = (lane < 32) ? (xr * cs + xp * sn) : (xr * cs - xp * sn);
      if (unit < 16) {
        o *= qg[unit];
        qn[(size_t)(b * 2048 + s) * 1024 + unit * 64 + lane] = f2bf(o);
      } else {
        kn[(size_t)(b * 2048 + s) * 256 + (unit - 16) * 64 + lane] = f2bf(o);
      }
    }
  }
}

// ---------------- causal GQA flash attention ----------------
// grid (S/64, B*H). 4 waves x 16 q-rows. KVBLK=64.
__global__ __launch_bounds__(256) void k_attn(const unsigned short* __restrict__ qn,
                                              const unsigned short* __restrict__ kn,
                                              const unsigned short* __restrict__ qkv,
                                              unsigned short* __restrict__ yb) {
  __shared__ unsigned short Ks[64 * 64];      // [key][d], XOR-swizzled
  __shared__ unsigned short Vt[64 * 64];      // [d][key], XOR-swizzled
  __shared__ unsigned short Ps[4][16 * 64];   // per-wave P, XOR-swizzled
  const int tid = threadIdx.x;
  const int wid = tid >> 6, lane = tid & 63;
  const int g = lane >> 4, r16 = lane & 15;
  const int qx = blockIdx.x, bh = blockIdx.y;
  const int b = bh >> 4, h = bh & 15, hv = h >> 2;
  const int q0 = qx * 64;

  bf16x8 aq0, aq1;
  {
    const unsigned short* qp =
        qn + (size_t)(b * 2048 + q0 + wid * 16 + r16) * 1024 + h * 64 + g * 8;
    aq0 = *(const bf16x8*)qp;
    aq1 = *(const bf16x8*)(qp + 32);
  }
  f32x4 yacc[4];
#pragma unroll
  for (int i = 0; i < 4; ++i) yacc[i] = f32x4{0.f, 0.f, 0.f, 0.f};
  float mrun[4], lrun[4];
#pragma unroll
  for (int j = 0; j < 4; ++j) { mrun[j] = -INFINITY; lrun[j] = 0.f; }

  const int cb = (lane & 7) * 16;

  for (int kv = 0; kv <= qx; ++kv) {
    const int k0 = kv * 64;
    // stage K tile (8KB) via global_load_lds, swizzled source
#pragma unroll
    for (int c = 0; c < 2; ++c) {
      int i = wid * 2 + c;
      int row = i * 8 + (lane >> 3);
      int sc = cb ^ ((row & 7) << 4);
      g2l16((const char*)(kn + (size_t)(b * 2048 + k0 + row) * 256 + hv * 64) + sc,
            (char*)Ks + i * 1024);
    }
    // stage V^T (reg-staged transpose), swizzled
#pragma unroll
    for (int r = 0; r < 2; ++r) {
      int krow = r * 32 + (tid >> 3);
      int d8 = (tid & 7) * 8;
      u16x8 v = *(const u16x8*)(qkv + (size_t)(b * 2048 + k0 + krow) * 1536 + 1280 + hv * 64 + d8);
#pragma unroll
      for (int j = 0; j < 8; ++j) {
        int d = d8 + j;
        int byte = d * 128 + ((krow * 2) ^ ((d & 7) << 4));
        *(unsigned short*)((char*)Vt + byte) = v[j];
      }
    }
    __syncthreads();

    // QK^T: 4 subtiles of 16 keys; scores layout col=key(lane&15), row=q((lane>>4)*4+j)
    float sm[4][4];
#pragma unroll
    for (int sub = 0; sub < 4; ++sub) {
      int krow = sub * 16 + r16;
      int base = krow * 128, sw = (krow & 7) << 4;
      bf16x8 kf0 = *(const bf16x8*)((const char*)Ks + base + ((g * 16) ^ sw));
      bf16x8 kf1 = *(const bf16x8*)((const char*)Ks + base + ((g * 16 + 64) ^ sw));
      f32x4 s = f32x4{0.f, 0.f, 0.f, 0.f};
      s = __builtin_amdgcn_mfma_f32_16x16x32_bf16(aq0, kf0, s, 0, 0, 0);
      s = __builtin_amdgcn_mfma_f32_16x16x32_bf16(aq1, kf1, s, 0, 0, 0);
      int kglob = k0 + sub * 16 + r16;
#pragma unroll
      for (int j = 0; j < 4; ++j) {
        int qglob = q0 + wid * 16 + g * 4 + j;
        sm[sub][j] = (kglob > qglob) ? -INFINITY : s[j] * 0.125f;
      }
    }
    // online softmax (row stats across the 16 lanes of lane&15)
#pragma unroll
    for (int j = 0; j < 4; ++j) {
      float mx = fmaxf(fmaxf(sm[0][j], sm[1][j]), fmaxf(sm[2][j], sm[3][j]));
      mx = fmaxf(mx, __shfl_xor(mx, 1));
      mx = fmaxf(mx, __shfl_xor(mx, 2));
      mx = fmaxf(mx, __shfl_xor(mx, 4));
      mx = fmaxf(mx, __shfl_xor(mx, 8));
      float mnew = fmaxf(mrun[j], mx);
      float f = __expf(mrun[j] - mnew);
      float psum = 0.f;
#pragma unroll
      for (int sub = 0; sub < 4; ++sub) {
        float p = __expf(sm[sub][j] - mnew);
        sm[sub][j] = p;
        psum += p;
      }
      psum += __shfl_xor(psum, 1);
      psum += __shfl_xor(psum, 2);
      psum += __shfl_xor(psum, 4);
      psum += __shfl_xor(psum, 8);
      lrun[j] = lrun[j] * f + psum;
      mrun[j] = mnew;
#pragma unroll
      for (int dt = 0; dt < 4; ++dt) yacc[dt][j] *= f;
    }
    // write P to per-wave LDS (swizzled); same-wave RAW -> no barrier needed
#pragma unroll
    for (int sub = 0; sub < 4; ++sub)
#pragma unroll
      for (int j = 0; j < 4; ++j) {
        int prow = g * 4 + j;
        int byte = prow * 128 + ((sub * 32 + r16 * 2) ^ ((prow & 7) << 4));
        *(unsigned short*)((char*)Ps[wid] + byte) = f2bf(sm[sub][j]);
      }
    // PV
    {
      int base = r16 * 128, sw = (r16 & 7) << 4;
      bf16x8 pa0 = *(const bf16x8*)((const char*)Ps[wid] + base + ((g * 16) ^ sw));
      bf16x8 pa1 = *(const bf16x8*)((const char*)Ps[wid] + base + ((g * 16 + 64) ^ sw));
#pragma unroll
      for (int dt = 0; dt < 4; ++dt) {
        int vrow = dt * 16 + r16;
        int vbase = vrow * 128, vsw = (vrow & 7) << 4;
        bf16x8 vf0 = *(const bf16x8*)((const char*)Vt + vbase + ((g * 16) ^ vsw));
        bf16x8 vf1 = *(const bf16x8*)((const char*)Vt + vbase + ((g * 16 + 64) ^ vsw));
        yacc[dt] = __builtin_amdgcn_mfma_f32_16x16x32_bf16(pa0, vf0, yacc[dt], 0, 0, 0);
        yacc[dt] = __builtin_amdgcn_mfma_f32_16x16x32_bf16(pa1, vf1, yacc[dt], 0, 0, 0);
      }
    }
    __syncthreads();
  }
  // normalize + store y (token-major [B*S][1024])
#pragma unroll
  for (int j = 0; j < 4; ++j) {
    float inv = 1.0f / lrun[j];
#pragma unroll
    for (int dt = 0; dt < 4; ++dt) {
      int row = q0 + wid * 16 + g * 4 + j;
      int col = h * 64 + dt * 16 + r16;
      yb[(size_t)(b * 2048 + row) * 1024 + col] = f2bf(yacc[dt][j] * inv);
    }
  }
}

// ---------------- launch ----------------
extern "C" void kernel_launch(void* const* d_in, const int* in_sizes, int n_in,
                              void* d_out, int out_size, void* d_ws, size_t ws_size,
                              hipStream_t stream) {
  (void)in_sizes; (void)n_in; (void)out_size; (void)ws_size;
  const float* x  = (const float*)d_in[0];
  const float* Wq = (const float*)d_in[1];
  const float* Wk = (const float*)d_in[2];
  const float* Wv = (const float*)d_in[3];
  const float* Wo = (const float*)d_in[4];
  const float* qg = (const float*)d_in[5];

  char* ws = (char*)d_ws;
  unsigned short* xb   = (unsigned short*)(ws);             // 16 MB  [8192][1024]
  unsigned short* wcat = (unsigned short*)(ws + 16777216);  // 3 MB   [1536][1024]
  unsigned short* wob  = (unsigned short*)(ws + 19922944);  // 2 MB   [1024][1024]
  unsigned short* qn   = (unsigned short*)(ws + 22020096);  // 16 MB  [8192][1024]
  unsigned short* kn   = (unsigned short*)(ws + 38797312);  // 4 MB   [8192][256]
  unsigned short* yb   = xb;                                // alias: xb dead after QKV GEMM
  unsigned short* qkv  = (unsigned short*)d_out;            // 25 MB scratch in d_out (f32 out = 32 MB)

  k_cvt<<<4096, 256, 0, stream>>>(x, xb, 8388608);
  k_cvt<<<512, 256, 0, stream>>>(Wq, wcat, 1048576);
  k_cvt<<<128, 256, 0, stream>>>(Wk, wcat + 1048576, 262144);
  k_cvt<<<128, 256, 0, stream>>>(Wv, wcat + 1310720, 262144);
  k_cvt<<<512, 256, 0, stream>>>(Wo, wob, 1048576);

  k_gemm_bt<unsigned short><<<dim3(64, 12), 256, 0, stream>>>(xb, wcat, qkv, 8192, 1536, 1024);
  k_normrope<<<512, 256, 0, stream>>>(qkv, qg, qn, kn);
  k_attn<<<dim3(32, 64), 256, 0, stream>>>(qn, kn, qkv, yb);
  k_gemm_bt<float><<<dim3(64, 8), 256, 0, stream>>>(yb, wob, (float*)d_out, 8192, 1024, 1024);
}

// Round 2
// 285.156 us; speedup vs baseline: 1.5451x; 1.5451x over previous
//
#include <hip/hip_runtime.h>

typedef float f32x4 __attribute__((ext_vector_type(4)));
typedef float f32x16 __attribute__((ext_vector_type(16)));
typedef __bf16 bf16x8 __attribute__((ext_vector_type(8)));
typedef unsigned short u16x8 __attribute__((ext_vector_type(8)));
typedef int i32x2 __attribute__((ext_vector_type(2)));
typedef int i32x4 __attribute__((ext_vector_type(4)));

#define DEV static __device__ __forceinline__

DEV float bf2f(unsigned short h) {
  unsigned int u = ((unsigned int)h) << 16;
  return __builtin_bit_cast(float, u);
}
DEV unsigned short f2bf(float f) {
  unsigned int u = __builtin_bit_cast(unsigned int, f);
  u += 0x7fff + ((u >> 16) & 1);   // RTNE
  return (unsigned short)(u >> 16);
}

DEV void g2l16(const void* g, void* l) {
  __builtin_amdgcn_global_load_lds(
      (const __attribute__((address_space(1))) void*)g,
      (__attribute__((address_space(3))) void*)l, 16, 0, 0);
}

DEV unsigned int cvtpk(float lo, float hi) {
  unsigned int r;
  asm("v_cvt_pk_bf16_f32 %0, %1, %2" : "=v"(r) : "v"(lo), "v"(hi));
  return r;
}

// ---------------- fp32 -> bf16 convert (n % 8 == 0) ----------------
__global__ __launch_bounds__(256) void k_cvt(const float* __restrict__ in,
                                             unsigned short* __restrict__ out, int n) {
  int i = (blockIdx.x * 256 + threadIdx.x) * 8;
  if (i >= n) return;
  float4 a = *(const float4*)(in + i);
  float4 b = *(const float4*)(in + i + 4);
  u16x8 r;
  r[0] = f2bf(a.x); r[1] = f2bf(a.y); r[2] = f2bf(a.z); r[3] = f2bf(a.w);
  r[4] = f2bf(b.x); r[5] = f2bf(b.y); r[6] = f2bf(b.z); r[7] = f2bf(b.w);
  *(u16x8*)(out + i) = r;
}

// ---------------- NT GEMM: C[M,N] = A[M,K] * B[N,K]^T  (m97 structure) ----------------
template <typename OUT>
__global__ __launch_bounds__(256) void k_gemm_bt(const unsigned short* __restrict__ A,
                                                 const unsigned short* __restrict__ B,
                                                 OUT* __restrict__ C, int M, int N, int K) {
  __shared__ unsigned short As[128 * 64];
  __shared__ unsigned short Bs[128 * 64];
  const int tid = threadIdx.x;
  const int wid = tid >> 6, lane = tid & 63;
  const int g = lane >> 4, r16 = lane & 15;
  const int m0 = blockIdx.x * 128, n0 = blockIdx.y * 128;
  const int wr = wid >> 1, wc = wid & 1;

  f32x4 acc[4][4];
#pragma unroll
  for (int i = 0; i < 4; ++i)
#pragma unroll
    for (int j = 0; j < 4; ++j) acc[i][j] = f32x4{0.f, 0.f, 0.f, 0.f};

  const int cb = (lane & 7) * 16;

  for (int k0 = 0; k0 < K; k0 += 64) {
#pragma unroll
    for (int c = 0; c < 4; ++c) {
      int i = wid * 4 + c;
      int row = i * 8 + (lane >> 3);
      int sc = cb ^ ((row & 7) << 4);
      g2l16((const char*)A + ((size_t)(m0 + row) * K + k0) * 2 + sc, (char*)As + i * 1024);
      g2l16((const char*)B + ((size_t)(n0 + row) * K + k0) * 2 + sc, (char*)Bs + i * 1024);
    }
    __syncthreads();
#pragma unroll
    for (int kh = 0; kh < 2; ++kh) {
      bf16x8 af[4], bfr[4];
#pragma unroll
      for (int m = 0; m < 4; ++m) {
        int row = wr * 64 + m * 16 + r16;
        int byte = row * 128 + ((g * 16 + kh * 64) ^ ((row & 7) << 4));
        af[m] = *(const bf16x8*)((const char*)As + byte);
      }
#pragma unroll
      for (int n = 0; n < 4; ++n) {
        int row = wc * 64 + n * 16 + r16;
        int byte = row * 128 + ((g * 16 + kh * 64) ^ ((row & 7) << 4));
        bfr[n] = *(const bf16x8*)((const char*)Bs + byte);
      }
#pragma unroll
      for (int m = 0; m < 4; ++m)
#pragma unroll
        for (int n = 0; n < 4; ++n)
          acc[m][n] = __builtin_amdgcn_mfma_f32_16x16x32_bf16(af[m], bfr[n], acc[m][n], 0, 0, 0);
    }
    __syncthreads();
  }
#pragma unroll
  for (int m = 0; m < 4; ++m)
#pragma unroll
    for (int n = 0; n < 4; ++n)
#pragma unroll
      for (int j = 0; j < 4; ++j) {
        int row = m0 + wr * 64 + m * 16 + g * 4 + j;
        int col = n0 + wc * 64 + n * 16 + r16;
        float v = acc[m][n][j];
        if constexpr (sizeof(OUT) == 2)
          C[(size_t)row * N + col] = f2bf(v);
        else
          C[(size_t)row * N + col] = v;
      }
}

// ---------------- RMSNorm + RoPE + q_gain epilogue ----------------
// qkv: [B*S][1536] bf16 (q 0..1023, k 1024..1279, v 1280..1535)
// q additionally scaled by 0.125*log2(e) so attention can use exp2 directly.
__global__ __launch_bounds__(256) void k_normrope(const unsigned short* __restrict__ qkv,
                                                  const float* __restrict__ qg,
                                                  unsigned short* __restrict__ qn,
                                                  unsigned short* __restrict__ kn) {
  const int wid = threadIdx.x >> 6, lane = threadIdx.x & 63;
  const int b = blockIdx.x >> 7;
  const int s0 = (blockIdx.x & 127) * 16;
  const int dh = lane & 31;
  const float inv_freq = powf(10000.0f, -(float)dh * (1.0f / 32.0f));
  for (int t = 0; t < 16; ++t) {
    const int s = s0 + t;
    float sn, cs;
    sincosf((float)s * inv_freq, &sn, &cs);
    const size_t base = (size_t)(b * 2048 + s) * 1536;
#pragma unroll
    for (int u = 0; u < 5; ++u) {
      const int unit = wid * 5 + u;  // 0..15 = q heads, 16..19 = k heads
      const int col = (unit < 16) ? unit * 64 : 1024 + (unit - 16) * 64;
      float v = bf2f(qkv[base + col + lane]);
      float ss = v * v;
      ss += __shfl_xor(ss, 1);  ss += __shfl_xor(ss, 2);  ss += __shfl_xor(ss, 4);
      ss += __shfl_xor(ss, 8);  ss += __shfl_xor(ss, 16); ss += __shfl_xor(ss, 32);
      float xr = v * rsqrtf(ss * (1.0f / 64.0f) + 1e-6f);
      float xp = __shfl_xor(xr, 32);
      float o = (lane < 32) ? (xr * cs + xp * sn) : (xr * cs - xp * sn);
      if (unit < 16) {
        o *= qg[unit] * 0.18033688011112042f;  // fold 1/8 * log2(e) into q
        qn[(size_t)(b * 2048 + s) * 1024 + unit * 64 + lane] = f2bf(o);
      } else {
        kn[(size_t)(b * 2048 + s) * 256 + (unit - 16) * 64 + lane] = f2bf(o);
      }
    }
  }
}

// ---------------- V transpose: qkv v-part -> vt[b][hv][dim64][S] ----------------
// conflict-free swizzle: swz(key) = ((key&7) ^ ((key>>3)&7)) << 4
__global__ __launch_bounds__(256) void k_vt(const unsigned short* __restrict__ qkv,
                                            unsigned short* __restrict__ vt) {
  __shared__ unsigned short T[64 * 64];
  const int tid = threadIdx.x;
  const int b = blockIdx.y >> 2, hv = blockIdx.y & 3;
  const int k0 = blockIdx.x * 64;
#pragma unroll
  for (int pass = 0; pass < 2; ++pass) {
    int key = pass * 32 + (tid >> 3);
    int d8 = (tid & 7) * 8;
    u16x8 v = *(const u16x8*)(qkv + (size_t)(b * 2048 + k0 + key) * 1536 + 1280 + hv * 64 + d8);
    int byte = key * 128 + ((d8 * 2) ^ ((((key & 7) ^ (key >> 3)) & 7) << 4));
    *(u16x8*)((char*)T + byte) = v;
  }
  __syncthreads();
#pragma unroll
  for (int pass = 0; pass < 2; ++pass) {
    int dim = pass * 32 + (tid >> 3);
    int k8 = (tid & 7) * 8;
    u16x8 o;
#pragma unroll
    for (int j = 0; j < 8; ++j) {
      int key = k8 + j;
      int byte = key * 128 + ((dim * 2) ^ ((((key & 7) ^ (key >> 3)) & 7) << 4));
      o[j] = *(const unsigned short*)((const char*)T + byte);
    }
    *(u16x8*)(vt + ((size_t)(b * 4 + hv) * 64 + dim) * 2048 + k0 + k8) = o;
  }
}

// ---------------- causal GQA flash attention, swapped-QK 32x32 ----------------
// grid (16, B*H) desc-qx. 4 waves x 32 q-rows (128/block). KVBLK=64.
// S^T = mfma(K, Q): lane owns q = lane&31; softmax state is per-lane scalar.
// O^T = mfma(V^T, P^T): D col = lane&31 = q stays aligned with softmax state.
__global__ __launch_bounds__(256) void k_attn2(const unsigned short* __restrict__ qn,
                                               const unsigned short* __restrict__ kn,
                                               const unsigned short* __restrict__ vt,
                                               unsigned short* __restrict__ yb) {
  __shared__ unsigned short SMEM[2 * 64 * 64];  // Ks | Vts, 16KB
  unsigned short* Ks = SMEM;
  unsigned short* Vts = SMEM + 64 * 64;
  const int tid = threadIdx.x;
  const int wid = tid >> 6, lane = tid & 63;
  const int hi = lane >> 5, l31 = lane & 31;
  const int qx = (int)gridDim.x - 1 - (int)blockIdx.x;  // descending work order
  const int bh = blockIdx.y, b = bh >> 4, h = bh & 15, hv = h >> 2;
  const int q0w = qx * 128 + wid * 32;
  const int qglob = q0w + l31;
  const size_t tok0 = (size_t)b * 2048;

  bf16x8 qf[4];
#pragma unroll
  for (int m = 0; m < 4; ++m)
    qf[m] = *(const bf16x8*)(qn + (tok0 + qglob) * 1024 + h * 64 + m * 16 + hi * 8);

  f32x16 oacc[2];
#pragma unroll
  for (int db = 0; db < 2; ++db)
#pragma unroll
    for (int r = 0; r < 16; ++r) oacc[db][r] = 0.f;
  float mrun = -INFINITY, lrun = 0.f;

  const int nt = qx * 2 + 2;
  const int swl = (l31 & 7) << 4;

  for (int t = 0; t < nt; ++t) {
    const int k0 = t * 64;
    // ---- stage K [64 keys][64 d] and V^T [64 d][64 keys], XOR-swizzled via source ----
#pragma unroll
    for (int c = 0; c < 2; ++c) {
      int i = wid * 2 + c;
      int row = i * 8 + (lane >> 3);
      int sc = ((lane & 7) * 16) ^ ((row & 7) << 4);
      g2l16((const char*)(kn + (tok0 + k0 + row) * 256 + hv * 64) + sc, (char*)Ks + i * 1024);
    }
#pragma unroll
    for (int c = 0; c < 2; ++c) {
      int i = wid * 2 + c;
      int row = i * 8 + (lane >> 3);
      int sc = ((lane & 7) * 16) ^ ((row & 7) << 4);
      g2l16((const char*)(vt + ((size_t)(b * 4 + hv) * 64 + row) * 2048 + k0) + sc,
            (char*)Vts + i * 1024);
    }
    __syncthreads();

    if (k0 <= q0w + 31) {  // wave has visible keys in this tile
      // ---- S^T[key][q] = K · Q^T ----
      f32x16 s[2];
#pragma unroll
      for (int kt = 0; kt < 2; ++kt) {
        f32x16 acc;
#pragma unroll
        for (int r = 0; r < 16; ++r) acc[r] = 0.f;
        const int krow = kt * 32 + l31;
        const char* kbase = (const char*)Ks + krow * 128;
        const int ksw = (krow & 7) << 4;
#pragma unroll
        for (int m = 0; m < 4; ++m) {
          bf16x8 kf = *(const bf16x8*)(kbase + ((m * 32 + hi * 16) ^ ksw));
          acc = __builtin_amdgcn_mfma_f32_32x32x16_bf16(kf, qf[m], acc, 0, 0, 0);
        }
        s[kt] = acc;
      }
      // ---- causal mask (only near-diagonal tiles) ----
      if (k0 + 63 > q0w) {
#pragma unroll
        for (int kt = 0; kt < 2; ++kt)
#pragma unroll
          for (int r = 0; r < 16; ++r) {
            int key = k0 + kt * 32 + (r & 3) + 8 * (r >> 2) + 4 * hi;
            if (key > qglob) s[kt][r] = -INFINITY;
          }
      }
      // ---- online softmax (per-lane scalar state, scores already in log2 domain) ----
      float red[16];
#pragma unroll
      for (int r = 0; r < 16; ++r) red[r] = fmaxf(s[0][r], s[1][r]);
#pragma unroll
      for (int r = 0; r < 8; ++r) red[r] = fmaxf(red[r], red[r + 8]);
#pragma unroll
      for (int r = 0; r < 4; ++r) red[r] = fmaxf(red[r], red[r + 4]);
      float mx = fmaxf(fmaxf(red[0], red[1]), fmaxf(red[2], red[3]));
      mx = fmaxf(mx, __shfl_xor(mx, 32));
      float mnew = fmaxf(mrun, mx);
      float fsc = exp2f(mrun - mnew);
#pragma unroll
      for (int kt = 0; kt < 2; ++kt)
#pragma unroll
        for (int r = 0; r < 16; ++r) s[kt][r] = exp2f(s[kt][r] - mnew);
      float sr[16];
#pragma unroll
      for (int r = 0; r < 16; ++r) sr[r] = s[0][r] + s[1][r];
#pragma unroll
      for (int r = 0; r < 8; ++r) sr[r] += sr[r + 8];
#pragma unroll
      for (int r = 0; r < 4; ++r) sr[r] += sr[r + 4];
      float ps = (sr[0] + sr[1]) + (sr[2] + sr[3]);
      ps += __shfl_xor(ps, 32);
      lrun = lrun * fsc + ps;
      mrun = mnew;
#pragma unroll
      for (int db = 0; db < 2; ++db)
#pragma unroll
        for (int r = 0; r < 16; ++r) oacc[db][r] *= fsc;
      // ---- P -> bf16 A/B-frag words via cvt_pk + permlane32_swap (T12) ----
      i32x4 paw[4];
#pragma unroll
      for (int kt = 0; kt < 2; ++kt)
#pragma unroll
        for (int half = 0; half < 2; ++half) {
          int bs = half * 8;
          unsigned int a0 = cvtpk(s[kt][bs + 0], s[kt][bs + 1]);
          unsigned int a1 = cvtpk(s[kt][bs + 2], s[kt][bs + 3]);
          unsigned int b0 = cvtpk(s[kt][bs + 4], s[kt][bs + 5]);
          unsigned int b1 = cvtpk(s[kt][bs + 6], s[kt][bs + 7]);
          i32x2 r0 = __builtin_amdgcn_permlane32_swap((int)a0, (int)b0, false, false);
          i32x2 r1 = __builtin_amdgcn_permlane32_swap((int)a1, (int)b1, false, false);
          i32x4 w;
          w[0] = r0[0]; w[1] = r1[0]; w[2] = r0[1]; w[3] = r1[1];
          paw[kt * 2 + half] = w;
        }
      // ---- O^T += V^T · P^T ----
#pragma unroll
      for (int db = 0; db < 2; ++db) {
        const int vrow = db * 32 + l31;
        const char* vbase = (const char*)Vts + vrow * 128;
        const int vsw = (vrow & 7) << 4;
#pragma unroll
        for (int ks = 0; ks < 4; ++ks) {
          bf16x8 vf = *(const bf16x8*)(vbase + ((ks * 32 + hi * 16) ^ vsw));
          oacc[db] = __builtin_amdgcn_mfma_f32_32x32x16_bf16(
              vf, __builtin_bit_cast(bf16x8, paw[ks]), oacc[db], 0, 0, 0);
        }
      }
    }
    __syncthreads();
  }

  // ---- epilogue: O^T -> per-wave LDS transpose -> coalesced row store ----
  const float inv = 1.0f / lrun;
  char* obase = (char*)SMEM + wid * 4096;
#pragma unroll
  for (int db = 0; db < 2; ++db)
#pragma unroll
    for (int i = 0; i < 8; ++i) {
      int r = 2 * i;
      int dim = db * 32 + (r & 3) + 8 * (r >> 2) + 4 * hi;
      unsigned int w = (unsigned int)f2bf(oacc[db][r] * inv) |
                       ((unsigned int)f2bf(oacc[db][r + 1] * inv) << 16);
      *(unsigned int*)(obase + l31 * 128 + ((dim * 2) ^ swl)) = w;
    }
  __syncthreads();
#pragma unroll
  for (int it = 0; it < 4; ++it) {
    int cc = it * 2 + hi;
    i32x4 w = *(const i32x4*)(obase + l31 * 128 + ((cc * 16) ^ swl));
    *(i32x4*)(yb + (tok0 + q0w + l31) * 1024 + h * 64 + cc * 8) = w;
  }
}

// ---------------- launch ----------------
extern "C" void kernel_launch(void* const* d_in, const int* in_sizes, int n_in,
                              void* d_out, int out_size, void* d_ws, size_t ws_size,
                              hipStream_t stream) {
  (void)in_sizes; (void)n_in; (void)out_size; (void)ws_size;
  const float* x  = (const float*)d_in[0];
  const float* Wq = (const float*)d_in[1];
  const float* Wk = (const float*)d_in[2];
  const float* Wv = (const float*)d_in[3];
  const float* Wo = (const float*)d_in[4];
  const float* qg = (const float*)d_in[5];

  char* ws = (char*)d_ws;
  unsigned short* xb   = (unsigned short*)(ws);             // 16 MB  [8192][1024]
  unsigned short* wcat = (unsigned short*)(ws + 16777216);  // 3 MB   [1536][1024]
  unsigned short* wob  = (unsigned short*)(ws + 19922944);  // 2 MB   [1024][1024]
  unsigned short* qn   = (unsigned short*)(ws + 22020096);  // 16 MB  [8192][1024]
  unsigned short* kn   = (unsigned short*)(ws + 38797312);  // 4 MB   [8192][256]
  unsigned short* yb   = xb;                                // alias: xb dead after QKV GEMM
  unsigned short* qkv  = (unsigned short*)d_out;            // 24 MB scratch in d_out
  unsigned short* vt   = (unsigned short*)((char*)d_out + 25165824);  // 4 MB [16][64][2048]

  k_cvt<<<4096, 256, 0, stream>>>(x, xb, 8388608);
  k_cvt<<<512, 256, 0, stream>>>(Wq, wcat, 1048576);
  k_cvt<<<128, 256, 0, stream>>>(Wk, wcat + 1048576, 262144);
  k_cvt<<<128, 256, 0, stream>>>(Wv, wcat + 1310720, 262144);
  k_cvt<<<512, 256, 0, stream>>>(Wo, wob, 1048576);

  k_gemm_bt<unsigned short><<<dim3(64, 12), 256, 0, stream>>>(xb, wcat, qkv, 8192, 1536, 1024);
  k_normrope<<<512, 256, 0, stream>>>(qkv, qg, qn, kn);
  k_vt<<<dim3(32, 16), 256, 0, stream>>>(qkv, vt);
  k_attn2<<<dim3(16, 64), 256, 0, stream>>>(qn, kn, vt, yb);
  k_gemm_bt<float><<<dim3(64, 8), 256, 0, stream>>>(yb, wob, (float*)d_out, 8192, 1024, 1024);
}

// Round 3
// 219.562 us; speedup vs baseline: 2.0067x; 1.2988x over previous
//
#include <hip/hip_runtime.h>

typedef float f32x4 __attribute__((ext_vector_type(4)));
typedef float f32x16 __attribute__((ext_vector_type(16)));
typedef __bf16 bf16x8 __attribute__((ext_vector_type(8)));
typedef unsigned short u16x8 __attribute__((ext_vector_type(8)));
typedef int i32x2 __attribute__((ext_vector_type(2)));
typedef int i32x4 __attribute__((ext_vector_type(4)));

#define DEV static __device__ __forceinline__

DEV float bf2f(unsigned short h) {
  unsigned int u = ((unsigned int)h) << 16;
  return __builtin_bit_cast(float, u);
}
DEV unsigned short f2bf(float f) {
  unsigned int u = __builtin_bit_cast(unsigned int, f);
  u += 0x7fff + ((u >> 16) & 1);   // RTNE
  return (unsigned short)(u >> 16);
}

DEV void g2l16(const void* g, void* l) {
  __builtin_amdgcn_global_load_lds(
      (const __attribute__((address_space(1))) void*)g,
      (__attribute__((address_space(3))) void*)l, 16, 0, 0);
}

DEV unsigned int cvtpk(float lo, float hi) {
  unsigned int r;
  asm("v_cvt_pk_bf16_f32 %0, %1, %2" : "=v"(r) : "v"(lo), "v"(hi));
  return r;
}

// ---------------- fp32 -> bf16 convert (n % 8 == 0) ----------------
__global__ __launch_bounds__(256) void k_cvt(const float* __restrict__ in,
                                             unsigned short* __restrict__ out, int n) {
  int i = (blockIdx.x * 256 + threadIdx.x) * 8;
  if (i >= n) return;
  float4 a = *(const float4*)(in + i);
  float4 b = *(const float4*)(in + i + 4);
  u16x8 r;
  r[0] = f2bf(a.x); r[1] = f2bf(a.y); r[2] = f2bf(a.z); r[3] = f2bf(a.w);
  r[4] = f2bf(b.x); r[5] = f2bf(b.y); r[6] = f2bf(b.z); r[7] = f2bf(b.w);
  *(u16x8*)(out + i) = r;
}

// ---------------- NT GEMM: C[M,N] = A[M,K] * B[N,K]^T  (m97 structure) ----------------
template <typename OUT>
__global__ __launch_bounds__(256) void k_gemm_bt(const unsigned short* __restrict__ A,
                                                 const unsigned short* __restrict__ B,
                                                 OUT* __restrict__ C, int M, int N, int K) {
  __shared__ unsigned short As[128 * 64];
  __shared__ unsigned short Bs[128 * 64];
  const int tid = threadIdx.x;
  const int wid = tid >> 6, lane = tid & 63;
  const int g = lane >> 4, r16 = lane & 15;
  const int m0 = blockIdx.x * 128, n0 = blockIdx.y * 128;
  const int wr = wid >> 1, wc = wid & 1;

  f32x4 acc[4][4];
#pragma unroll
  for (int i = 0; i < 4; ++i)
#pragma unroll
    for (int j = 0; j < 4; ++j) acc[i][j] = f32x4{0.f, 0.f, 0.f, 0.f};

  const int cb = (lane & 7) * 16;

  for (int k0 = 0; k0 < K; k0 += 64) {
#pragma unroll
    for (int c = 0; c < 4; ++c) {
      int i = wid * 4 + c;
      int row = i * 8 + (lane >> 3);
      int sc = cb ^ ((row & 7) << 4);
      g2l16((const char*)A + ((size_t)(m0 + row) * K + k0) * 2 + sc, (char*)As + i * 1024);
      g2l16((const char*)B + ((size_t)(n0 + row) * K + k0) * 2 + sc, (char*)Bs + i * 1024);
    }
    __syncthreads();
#pragma unroll
    for (int kh = 0; kh < 2; ++kh) {
      bf16x8 af[4], bfr[4];
#pragma unroll
      for (int m = 0; m < 4; ++m) {
        int row = wr * 64 + m * 16 + r16;
        int byte = row * 128 + ((g * 16 + kh * 64) ^ ((row & 7) << 4));
        af[m] = *(const bf16x8*)((const char*)As + byte);
      }
#pragma unroll
      for (int n = 0; n < 4; ++n) {
        int row = wc * 64 + n * 16 + r16;
        int byte = row * 128 + ((g * 16 + kh * 64) ^ ((row & 7) << 4));
        bfr[n] = *(const bf16x8*)((const char*)Bs + byte);
      }
#pragma unroll
      for (int m = 0; m < 4; ++m)
#pragma unroll
        for (int n = 0; n < 4; ++n)
          acc[m][n] = __builtin_amdgcn_mfma_f32_16x16x32_bf16(af[m], bfr[n], acc[m][n], 0, 0, 0);
    }
    __syncthreads();
  }
#pragma unroll
  for (int m = 0; m < 4; ++m)
#pragma unroll
    for (int n = 0; n < 4; ++n)
#pragma unroll
      for (int j = 0; j < 4; ++j) {
        int row = m0 + wr * 64 + m * 16 + g * 4 + j;
        int col = n0 + wc * 64 + n * 16 + r16;
        float v = acc[m][n][j];
        if constexpr (sizeof(OUT) == 2)
          C[(size_t)row * N + col] = f2bf(v);
        else
          C[(size_t)row * N + col] = v;
      }
}

// ---------------- RMSNorm + RoPE + q_gain epilogue ----------------
__global__ __launch_bounds__(256) void k_normrope(const unsigned short* __restrict__ qkv,
                                                  const float* __restrict__ qg,
                                                  unsigned short* __restrict__ qn,
                                                  unsigned short* __restrict__ kn) {
  const int wid = threadIdx.x >> 6, lane = threadIdx.x & 63;
  const int b = blockIdx.x >> 7;
  const int s0 = (blockIdx.x & 127) * 16;
  const int dh = lane & 31;
  const float inv_freq = powf(10000.0f, -(float)dh * (1.0f / 32.0f));
  for (int t = 0; t < 16; ++t) {
    const int s = s0 + t;
    float sn, cs;
    sincosf((float)s * inv_freq, &sn, &cs);
    const size_t base = (size_t)(b * 2048 + s) * 1536;
#pragma unroll
    for (int u = 0; u < 5; ++u) {
      const int unit = wid * 5 + u;  // 0..15 = q heads, 16..19 = k heads
      const int col = (unit < 16) ? unit * 64 : 1024 + (unit - 16) * 64;
      float v = bf2f(qkv[base + col + lane]);
      float ss = v * v;
      ss += __shfl_xor(ss, 1);  ss += __shfl_xor(ss, 2);  ss += __shfl_xor(ss, 4);
      ss += __shfl_xor(ss, 8);  ss += __shfl_xor(ss, 16); ss += __shfl_xor(ss, 32);
      float xr = v * rsqrtf(ss * (1.0f / 64.0f) + 1e-6f);
      float xp = __shfl_xor(xr, 32);
      float o = (lane < 32) ? (xr * cs + xp * sn) : (xr * cs - xp * sn);
      if (unit < 16) {
        o *= qg[unit] * 0.18033688011112042f;  // fold 1/8 * log2(e) into q
        qn[(size_t)(b * 2048 + s) * 1024 + unit * 64 + lane] = f2bf(o);
      } else {
        kn[(size_t)(b * 2048 + s) * 256 + (unit - 16) * 64 + lane] = f2bf(o);
      }
    }
  }
}

// ---------------- V transpose: qkv v-part -> vt[b][hv][dim64][S] ----------------
__global__ __launch_bounds__(256) void k_vt(const unsigned short* __restrict__ qkv,
                                            unsigned short* __restrict__ vt) {
  __shared__ unsigned short T[64 * 64];
  const int tid = threadIdx.x;
  const int b = blockIdx.y >> 2, hv = blockIdx.y & 3;
  const int k0 = blockIdx.x * 64;
#pragma unroll
  for (int pass = 0; pass < 2; ++pass) {
    int key = pass * 32 + (tid >> 3);
    int d8 = (tid & 7) * 8;
    u16x8 v = *(const u16x8*)(qkv + (size_t)(b * 2048 + k0 + key) * 1536 + 1280 + hv * 64 + d8);
    int byte = key * 128 + ((d8 * 2) ^ ((((key & 7) ^ (key >> 3)) & 7) << 4));
    *(u16x8*)((char*)T + byte) = v;
  }
  __syncthreads();
#pragma unroll
  for (int pass = 0; pass < 2; ++pass) {
    int dim = pass * 32 + (tid >> 3);
    int k8 = (tid & 7) * 8;
    u16x8 o;
#pragma unroll
    for (int j = 0; j < 8; ++j) {
      int key = k8 + j;
      int byte = key * 128 + ((dim * 2) ^ ((((key & 7) ^ (key >> 3)) & 7) << 4));
      o[j] = *(const unsigned short*)((const char*)T + byte);
    }
    *(u16x8*)(vt + ((size_t)(b * 4 + hv) * 64 + dim) * 2048 + k0 + k8) = o;
  }
}

// ---------------- causal GQA flash attention, swapped-QK 32x32, 2-phase dbuf ----------------
// 1D grid 1024, longest blocks first. 4 waves x 32 q-rows. KVBLK=64.
__global__ __launch_bounds__(256) void k_attn2(const unsigned short* __restrict__ qn,
                                               const unsigned short* __restrict__ kn,
                                               const unsigned short* __restrict__ vt,
                                               unsigned short* __restrict__ yb) {
  __shared__ unsigned short SMEM[2 * 8192];  // 2 x (Ks 8KB | Vts 8KB) = 32KB
  const int tid = threadIdx.x;
  const int wid = tid >> 6, lane = tid & 63;
  const int hi = lane >> 5, l31 = lane & 31;
  const int flat = blockIdx.x;
  const int qx = 15 - (flat >> 6);  // all longest (qx=15) blocks dispatch first
  const int bh = flat & 63;
  const int b = bh >> 4, h = bh & 15, hv = h >> 2;
  const int q0w = qx * 128 + wid * 32;
  const int qglob = q0w + l31;
  const size_t tok0 = (size_t)b * 2048;
  const unsigned short* vtb = vt + (size_t)(b * 4 + hv) * 64 * 2048;

  bf16x8 qf[4];
#pragma unroll
  for (int m = 0; m < 4; ++m)
    qf[m] = *(const bf16x8*)(qn + (tok0 + qglob) * 1024 + h * 64 + m * 16 + hi * 8);

  f32x16 oacc[2];
#pragma unroll
  for (int db = 0; db < 2; ++db)
#pragma unroll
    for (int r = 0; r < 16; ++r) oacc[db][r] = 0.f;
  float mrun = -INFINITY, lrun = 0.f;

  const int nt = qx * 2 + 2;

  auto stage = [&](int T, int buf) {
    unsigned short* KsB = SMEM + buf * 8192;
    unsigned short* VtB = KsB + 4096;
    const int kk0 = T * 64;
#pragma unroll
    for (int c = 0; c < 2; ++c) {
      int i = wid * 2 + c;
      int row = i * 8 + (lane >> 3);
      int sc = ((lane & 7) * 16) ^ ((row & 7) << 4);
      g2l16((const char*)(kn + (tok0 + kk0 + row) * 256 + hv * 64) + sc, (char*)KsB + i * 1024);
      g2l16((const char*)(vtb + (size_t)row * 2048 + kk0) + sc, (char*)VtB + i * 1024);
    }
  };

  stage(0, 0);
  __syncthreads();

  int cur = 0;
  for (int t = 0; t < nt; ++t) {
    const int k0 = t * 64;
    if (t + 1 < nt) stage(t + 1, cur ^ 1);  // prefetch overlaps compute below

    if (k0 <= q0w + 31) {
      const unsigned short* KsB = SMEM + cur * 8192;
      const unsigned short* VtB = KsB + 4096;
      // ---- S^T[key][q] = K · Q^T ----
      f32x16 s[2];
#pragma unroll
      for (int kt = 0; kt < 2; ++kt) {
        f32x16 acc;
#pragma unroll
        for (int r = 0; r < 16; ++r) acc[r] = 0.f;
        const int krow = kt * 32 + l31;
        const char* kbase = (const char*)KsB + krow * 128;
        const int ksw = (krow & 7) << 4;
        __builtin_amdgcn_s_setprio(1);
#pragma unroll
        for (int m = 0; m < 4; ++m) {
          bf16x8 kf = *(const bf16x8*)(kbase + ((m * 32 + hi * 16) ^ ksw));
          acc = __builtin_amdgcn_mfma_f32_32x32x16_bf16(kf, qf[m], acc, 0, 0, 0);
        }
        __builtin_amdgcn_s_setprio(0);
        s[kt] = acc;
      }
      // ---- causal mask (near-diagonal tiles only) ----
      if (k0 + 63 > q0w) {
#pragma unroll
        for (int kt = 0; kt < 2; ++kt)
#pragma unroll
          for (int r = 0; r < 16; ++r) {
            int key = k0 + kt * 32 + (r & 3) + 8 * (r >> 2) + 4 * hi;
            if (key > qglob) s[kt][r] = -INFINITY;
          }
      }
      // ---- online softmax, per-lane scalar state, log2 domain, defer-max (T13) ----
      float red[16];
#pragma unroll
      for (int r = 0; r < 16; ++r) red[r] = fmaxf(s[0][r], s[1][r]);
#pragma unroll
      for (int r = 0; r < 8; ++r) red[r] = fmaxf(red[r], red[r + 8]);
#pragma unroll
      for (int r = 0; r < 4; ++r) red[r] = fmaxf(red[r], red[r + 4]);
      float mx = fmaxf(fmaxf(red[0], red[1]), fmaxf(red[2], red[3]));
      mx = fmaxf(mx, __shfl_xor(mx, 32));
      if (!__all(mx - mrun <= 8.0f)) {  // rescale only on real max growth
        float mnew = fmaxf(mrun, mx);
        float fsc = exp2f(mrun - mnew);
        lrun *= fsc;
#pragma unroll
        for (int db = 0; db < 2; ++db)
#pragma unroll
          for (int r = 0; r < 16; ++r) oacc[db][r] *= fsc;
        mrun = mnew;
      }
#pragma unroll
      for (int kt = 0; kt < 2; ++kt)
#pragma unroll
        for (int r = 0; r < 16; ++r) s[kt][r] = exp2f(s[kt][r] - mrun);
      float sr[16];
#pragma unroll
      for (int r = 0; r < 16; ++r) sr[r] = s[0][r] + s[1][r];
#pragma unroll
      for (int r = 0; r < 8; ++r) sr[r] += sr[r + 8];
#pragma unroll
      for (int r = 0; r < 4; ++r) sr[r] += sr[r + 4];
      float ps = (sr[0] + sr[1]) + (sr[2] + sr[3]);
      ps += __shfl_xor(ps, 32);
      lrun += ps;
      // ---- P -> bf16 frags via cvt_pk + permlane32_swap (T12) ----
      i32x4 paw[4];
#pragma unroll
      for (int kt = 0; kt < 2; ++kt)
#pragma unroll
        for (int half = 0; half < 2; ++half) {
          int bs = half * 8;
          unsigned int a0 = cvtpk(s[kt][bs + 0], s[kt][bs + 1]);
          unsigned int a1 = cvtpk(s[kt][bs + 2], s[kt][bs + 3]);
          unsigned int b0 = cvtpk(s[kt][bs + 4], s[kt][bs + 5]);
          unsigned int b1 = cvtpk(s[kt][bs + 6], s[kt][bs + 7]);
          i32x2 r0 = __builtin_amdgcn_permlane32_swap((int)a0, (int)b0, false, false);
          i32x2 r1 = __builtin_amdgcn_permlane32_swap((int)a1, (int)b1, false, false);
          i32x4 w;
          w[0] = r0[0]; w[1] = r1[0]; w[2] = r0[1]; w[3] = r1[1];
          paw[kt * 2 + half] = w;
        }
      // ---- O^T += V^T · P^T ----
#pragma unroll
      for (int db = 0; db < 2; ++db) {
        const int vrow = db * 32 + l31;
        const char* vbase = (const char*)VtB + vrow * 128;
        const int vsw = (vrow & 7) << 4;
        __builtin_amdgcn_s_setprio(1);
#pragma unroll
        for (int ks = 0; ks < 4; ++ks) {
          bf16x8 vf = *(const bf16x8*)(vbase + ((ks * 32 + hi * 16) ^ vsw));
          oacc[db] = __builtin_amdgcn_mfma_f32_32x32x16_bf16(
              vf, __builtin_bit_cast(bf16x8, paw[ks]), oacc[db], 0, 0, 0);
        }
        __builtin_amdgcn_s_setprio(0);
      }
    }
    __syncthreads();  // drains prefetch (vmcnt) + protects buffer swap
    cur ^= 1;
  }

  // ---- epilogue: O^T -> per-wave LDS transpose -> coalesced row store ----
  const float inv = 1.0f / lrun;
  const int swl = (l31 & 7) << 4;
  char* obase = (char*)SMEM + wid * 4096;
#pragma unroll
  for (int db = 0; db < 2; ++db)
#pragma unroll
    for (int i = 0; i < 8; ++i) {
      int r = 2 * i;
      int dim = db * 32 + (r & 3) + 8 * (r >> 2) + 4 * hi;
      unsigned int w = (unsigned int)f2bf(oacc[db][r] * inv) |
                       ((unsigned int)f2bf(oacc[db][r + 1] * inv) << 16);
      *(unsigned int*)(obase + l31 * 128 + ((dim * 2) ^ swl)) = w;
    }
  __syncthreads();
#pragma unroll
  for (int it = 0; it < 4; ++it) {
    int cc = it * 2 + hi;
    i32x4 w = *(const i32x4*)(obase + l31 * 128 + ((cc * 16) ^ swl));
    *(i32x4*)(yb + (tok0 + q0w + l31) * 1024 + h * 64 + cc * 8) = w;
  }
}

// ---------------- launch ----------------
extern "C" void kernel_launch(void* const* d_in, const int* in_sizes, int n_in,
                              void* d_out, int out_size, void* d_ws, size_t ws_size,
                              hipStream_t stream) {
  (void)in_sizes; (void)n_in; (void)out_size; (void)ws_size;
  const float* x  = (const float*)d_in[0];
  const float* Wq = (const float*)d_in[1];
  const float* Wk = (const float*)d_in[2];
  const float* Wv = (const float*)d_in[3];
  const float* Wo = (const float*)d_in[4];
  const float* qg = (const float*)d_in[5];

  char* ws = (char*)d_ws;
  unsigned short* xb   = (unsigned short*)(ws);             // 16 MB  [8192][1024]
  unsigned short* wcat = (unsigned short*)(ws + 16777216);  // 3 MB   [1536][1024]
  unsigned short* wob  = (unsigned short*)(ws + 19922944);  // 2 MB   [1024][1024]
  unsigned short* qn   = (unsigned short*)(ws + 22020096);  // 16 MB  [8192][1024]
  unsigned short* kn   = (unsigned short*)(ws + 38797312);  // 4 MB   [8192][256]
  unsigned short* yb   = xb;                                // alias: xb dead after QKV GEMM
  unsigned short* qkv  = (unsigned short*)d_out;            // 24 MB scratch in d_out
  unsigned short* vt   = (unsigned short*)((char*)d_out + 25165824);  // 4 MB [16][64][2048]

  k_cvt<<<4096, 256, 0, stream>>>(x, xb, 8388608);
  k_cvt<<<512, 256, 0, stream>>>(Wq, wcat, 1048576);
  k_cvt<<<128, 256, 0, stream>>>(Wk, wcat + 1048576, 262144);
  k_cvt<<<128, 256, 0, stream>>>(Wv, wcat + 1310720, 262144);
  k_cvt<<<512, 256, 0, stream>>>(Wo, wob, 1048576);

  k_gemm_bt<unsigned short><<<dim3(64, 12), 256, 0, stream>>>(xb, wcat, qkv, 8192, 1536, 1024);
  k_normrope<<<512, 256, 0, stream>>>(qkv, qg, qn, kn);
  k_vt<<<dim3(32, 16), 256, 0, stream>>>(qkv, vt);
  k_attn2<<<1024, 256, 0, stream>>>(qn, kn, vt, yb);
  k_gemm_bt<float><<<dim3(64, 8), 256, 0, stream>>>(yb, wob, (float*)d_out, 8192, 1024, 1024);
}

// Round 4
// 215.750 us; speedup vs baseline: 2.0422x; 1.0177x over previous
//
#include <hip/hip_runtime.h>

typedef float f32x4 __attribute__((ext_vector_type(4)));
typedef float f32x16 __attribute__((ext_vector_type(16)));
typedef __bf16 bf16x8 __attribute__((ext_vector_type(8)));
typedef unsigned short u16x8 __attribute__((ext_vector_type(8)));
typedef int i32x2 __attribute__((ext_vector_type(2)));
typedef int i32x4 __attribute__((ext_vector_type(4)));

#define DEV static __device__ __forceinline__
#define VMCNT(n) asm volatile("s_waitcnt vmcnt(" #n ")" ::: "memory")

DEV float bf2f(unsigned short h) {
  unsigned int u = ((unsigned int)h) << 16;
  return __builtin_bit_cast(float, u);
}
DEV unsigned short f2bf(float f) {
  unsigned int u = __builtin_bit_cast(unsigned int, f);
  u += 0x7fff + ((u >> 16) & 1);   // RTNE
  return (unsigned short)(u >> 16);
}

DEV void g2l16(const void* g, void* l) {
  __builtin_amdgcn_global_load_lds(
      (const __attribute__((address_space(1))) void*)g,
      (__attribute__((address_space(3))) void*)l, 16, 0, 0);
}

DEV void barrier_fence() {
  __builtin_amdgcn_s_barrier();
  asm volatile("" ::: "memory");
}

DEV unsigned int cvtpk(float lo, float hi) {
  unsigned int r;
  asm("v_cvt_pk_bf16_f32 %0, %1, %2" : "=v"(r) : "v"(lo), "v"(hi));
  return r;
}

// ---------------- fp32 -> bf16 convert (n % 8 == 0) ----------------
__global__ __launch_bounds__(256) void k_cvt(const float* __restrict__ in,
                                             unsigned short* __restrict__ out, int n) {
  int i = (blockIdx.x * 256 + threadIdx.x) * 8;
  if (i >= n) return;
  float4 a = *(const float4*)(in + i);
  float4 b = *(const float4*)(in + i + 4);
  u16x8 r;
  r[0] = f2bf(a.x); r[1] = f2bf(a.y); r[2] = f2bf(a.z); r[3] = f2bf(a.w);
  r[4] = f2bf(b.x); r[5] = f2bf(b.y); r[6] = f2bf(b.z); r[7] = f2bf(b.w);
  *(u16x8*)(out + i) = r;
}

// ---------------- NT GEMM, counted-vmcnt phase pipeline (T2+T3+T4+T5) ----------------
// C[M,N] = A[M,K] * B[N,K]^T. BN=256, BK=64, 512 threads (8 waves: 2m x 4n).
// Per K-tile t: 2 phases. Staging of tile t+1: P1 issues B (4x8KB), P2 issues
// A-half0, A-half1. Waits: P1 vmcnt(W1) [W1 = #issues of A-half1], P2 vmcnt(4)
// (next tile's B may stay in flight) or vmcnt(0) on the last tile.
template <int BM, typename OUT>
__global__ __launch_bounds__(512, 1) void k_gemm8(const unsigned short* __restrict__ A,
                                                  const unsigned short* __restrict__ B,
                                                  OUT* __restrict__ C, int M, int N, int K) {
  constexpr int MR = BM / 32;   // per-wave m-frags
  constexpr int MH = MR / 2;    // m-frags per phase
  __shared__ unsigned short sA[2][BM * 64];
  __shared__ unsigned short sB[2][256 * 64];
  const int tid = threadIdx.x;
  const int wid = tid >> 6, lane = tid & 63;
  const int wm = wid >> 2, wn = wid & 3;
  const int g = lane >> 4, r16 = lane & 15;
  const int m0 = blockIdx.x * BM, n0 = blockIdx.y * 256;
  const int NK = K >> 6;

  const int srow = (wid << 3) + (lane >> 3);  // 0..63 within an 8KB issue
  const int scolb = (lane & 7) << 4;          // byte col within 128B row

  f32x4 acc[MR][4];
#pragma unroll
  for (int i = 0; i < MR; ++i)
#pragma unroll
    for (int j = 0; j < 4; ++j) acc[i][j] = f32x4{0.f, 0.f, 0.f, 0.f};

  auto stageB = [&](int kt, int buf) {  // 4 issues (32 KB)
    const unsigned short* gb = B + (size_t)n0 * K + (kt << 6);
#pragma unroll
    for (int c = 0; c < 4; ++c) {
      int r = c * 64 + srow;
      int sc = scolb ^ ((r & 7) << 4);
      g2l16((const char*)(gb + (size_t)r * K) + sc,
            (char*)&sB[buf][c * 4096] + wid * 1024);
    }
  };
  auto stageA = [&](int kt, int buf, int part) {  // BM=256: 2 issues; BM=128: 1 issue
    const unsigned short* ga = A + (size_t)m0 * K + (kt << 6);
    if constexpr (BM == 256) {
#pragma unroll
      for (int c = 0; c < 2; ++c) {
        int r = c * 128 + part * 64 + srow;
        int sc = scolb ^ ((r & 7) << 4);
        g2l16((const char*)(ga + (size_t)r * K) + sc,
              (char*)&sA[buf][(c * 128 + part * 64) * 64] + wid * 1024);
      }
    } else {
      int rb = (wid >> 2) * 64 + part * 32 + ((wid & 3) << 3);  // wave-uniform base row
      int r = rb + (lane >> 3);
      int sc = scolb ^ ((r & 7) << 4);
      g2l16((const char*)(ga + (size_t)r * K) + sc, (char*)&sA[buf][rb * 64]);
    }
  };

  // prologue: tile 0 fully staged, A-half1 last (the "newest W1" of the ledger)
  stageB(0, 0);
  stageA(0, 0, 0);
  stageA(0, 0, 1);

  for (int kt = 0; kt < NK; ++kt) {
    const int cur = kt & 1;
    const bool pre = (kt + 1 < NK);

    // ---------- phase 0: m-half 0, all B ----------
    if constexpr (BM == 256) VMCNT(2); else VMCNT(1);
    barrier_fence();
    bf16x8 bfr[4][2];
#pragma unroll
    for (int fn = 0; fn < 4; ++fn) {
      int row = wn * 64 + fn * 16 + r16;
      const char* base = (const char*)&sB[cur][0] + row * 128;
      int sw = (row & 7) << 4;
#pragma unroll
      for (int kk = 0; kk < 2; ++kk)
        bfr[fn][kk] = *(const bf16x8*)(base + ((g * 16 + kk * 64) ^ sw));
    }
    bf16x8 af0[MH][2];
#pragma unroll
    for (int i = 0; i < MH; ++i) {
      int row = wm * (BM / 2) + i * 16 + r16;
      const char* base = (const char*)&sA[cur][0] + row * 128;
      int sw = (row & 7) << 4;
#pragma unroll
      for (int kk = 0; kk < 2; ++kk)
        af0[i][kk] = *(const bf16x8*)(base + ((g * 16 + kk * 64) ^ sw));
    }
    if (pre) stageB(kt + 1, cur ^ 1);
    __builtin_amdgcn_s_setprio(1);
#pragma unroll
    for (int kk = 0; kk < 2; ++kk)
#pragma unroll
      for (int i = 0; i < MH; ++i)
#pragma unroll
        for (int fn = 0; fn < 4; ++fn)
          acc[i][fn] = __builtin_amdgcn_mfma_f32_16x16x32_bf16(af0[i][kk], bfr[fn][kk],
                                                               acc[i][fn], 0, 0, 0);
    __builtin_amdgcn_s_setprio(0);

    // ---------- phase 1: m-half 1, B from registers ----------
    if (pre) VMCNT(4); else VMCNT(0);
    barrier_fence();
    bf16x8 af1[MH][2];
#pragma unroll
    for (int i = 0; i < MH; ++i) {
      int row = wm * (BM / 2) + (MH + i) * 16 + r16;
      const char* base = (const char*)&sA[cur][0] + row * 128;
      int sw = (row & 7) << 4;
#pragma unroll
      for (int kk = 0; kk < 2; ++kk)
        af1[i][kk] = *(const bf16x8*)(base + ((g * 16 + kk * 64) ^ sw));
    }
    if (pre) {
      stageA(kt + 1, cur ^ 1, 0);
      stageA(kt + 1, cur ^ 1, 1);
    }
    __builtin_amdgcn_s_setprio(1);
#pragma unroll
    for (int kk = 0; kk < 2; ++kk)
#pragma unroll
      for (int i = 0; i < MH; ++i)
#pragma unroll
        for (int fn = 0; fn < 4; ++fn)
          acc[MH + i][fn] = __builtin_amdgcn_mfma_f32_16x16x32_bf16(af1[i][kk], bfr[fn][kk],
                                                                    acc[MH + i][fn], 0, 0, 0);
    __builtin_amdgcn_s_setprio(0);
  }

  // ---------- epilogue ----------
#pragma unroll
  for (int fm = 0; fm < MR; ++fm)
#pragma unroll
    for (int fn = 0; fn < 4; ++fn)
#pragma unroll
      for (int j = 0; j < 4; ++j) {
        int row = m0 + wm * (BM / 2) + fm * 16 + g * 4 + j;
        int col = n0 + wn * 64 + fn * 16 + r16;
        float v = acc[fm][fn][j];
        if constexpr (sizeof(OUT) == 2)
          C[(size_t)row * N + col] = f2bf(v);
        else
          C[(size_t)row * N + col] = v;
      }
}

// ---------------- RMSNorm + RoPE + q_gain epilogue ----------------
__global__ __launch_bounds__(256) void k_normrope(const unsigned short* __restrict__ qkv,
                                                  const float* __restrict__ qg,
                                                  unsigned short* __restrict__ qn,
                                                  unsigned short* __restrict__ kn) {
  const int wid = threadIdx.x >> 6, lane = threadIdx.x & 63;
  const int b = blockIdx.x >> 7;
  const int s0 = (blockIdx.x & 127) * 16;
  const int dh = lane & 31;
  const float inv_freq = powf(10000.0f, -(float)dh * (1.0f / 32.0f));
  for (int t = 0; t < 16; ++t) {
    const int s = s0 + t;
    float sn, cs;
    sincosf((float)s * inv_freq, &sn, &cs);
    const size_t base = (size_t)(b * 2048 + s) * 1536;
#pragma unroll
    for (int u = 0; u < 5; ++u) {
      const int unit = wid * 5 + u;  // 0..15 = q heads, 16..19 = k heads
      const int col = (unit < 16) ? unit * 64 : 1024 + (unit - 16) * 64;
      float v = bf2f(qkv[base + col + lane]);
      float ss = v * v;
      ss += __shfl_xor(ss, 1);  ss += __shfl_xor(ss, 2);  ss += __shfl_xor(ss, 4);
      ss += __shfl_xor(ss, 8);  ss += __shfl_xor(ss, 16); ss += __shfl_xor(ss, 32);
      float xr = v * rsqrtf(ss * (1.0f / 64.0f) + 1e-6f);
      float xp = __shfl_xor(xr, 32);
      float o = (lane < 32) ? (xr * cs + xp * sn) : (xr * cs - xp * sn);
      if (unit < 16) {
        o *= qg[unit] * 0.18033688011112042f;  // fold 1/8 * log2(e) into q
        qn[(size_t)(b * 2048 + s) * 1024 + unit * 64 + lane] = f2bf(o);
      } else {
        kn[(size_t)(b * 2048 + s) * 256 + (unit - 16) * 64 + lane] = f2bf(o);
      }
    }
  }
}

// ---------------- V transpose: qkv v-part -> vt[b][hv][dim64][S] ----------------
__global__ __launch_bounds__(256) void k_vt(const unsigned short* __restrict__ qkv,
                                            unsigned short* __restrict__ vt) {
  __shared__ unsigned short T[64 * 64];
  const int tid = threadIdx.x;
  const int b = blockIdx.y >> 2, hv = blockIdx.y & 3;
  const int k0 = blockIdx.x * 64;
#pragma unroll
  for (int pass = 0; pass < 2; ++pass) {
    int key = pass * 32 + (tid >> 3);
    int d8 = (tid & 7) * 8;
    u16x8 v = *(const u16x8*)(qkv + (size_t)(b * 2048 + k0 + key) * 1536 + 1280 + hv * 64 + d8);
    int byte = key * 128 + ((d8 * 2) ^ ((((key & 7) ^ (key >> 3)) & 7) << 4));
    *(u16x8*)((char*)T + byte) = v;
  }
  __syncthreads();
#pragma unroll
  for (int pass = 0; pass < 2; ++pass) {
    int dim = pass * 32 + (tid >> 3);
    int k8 = (tid & 7) * 8;
    u16x8 o;
#pragma unroll
    for (int j = 0; j < 8; ++j) {
      int key = k8 + j;
      int byte = key * 128 + ((dim * 2) ^ ((((key & 7) ^ (key >> 3)) & 7) << 4));
      o[j] = *(const unsigned short*)((const char*)T + byte);
    }
    *(u16x8*)(vt + ((size_t)(b * 4 + hv) * 64 + dim) * 2048 + k0 + k8) = o;
  }
}

// ---------------- causal GQA flash attention, swapped-QK 32x32, 2-phase dbuf ----------------
__global__ __launch_bounds__(256) void k_attn2(const unsigned short* __restrict__ qn,
                                               const unsigned short* __restrict__ kn,
                                               const unsigned short* __restrict__ vt,
                                               unsigned short* __restrict__ yb) {
  __shared__ unsigned short SMEM[2 * 8192];  // 2 x (Ks 8KB | Vts 8KB) = 32KB
  const int tid = threadIdx.x;
  const int wid = tid >> 6, lane = tid & 63;
  const int hi = lane >> 5, l31 = lane & 31;
  const int flat = blockIdx.x;
  const int qx = 15 - (flat >> 6);  // longest (qx=15) blocks dispatch first
  const int bh = flat & 63;
  const int b = bh >> 4, h = bh & 15, hv = h >> 2;
  const int q0w = qx * 128 + wid * 32;
  const int qglob = q0w + l31;
  const size_t tok0 = (size_t)b * 2048;
  const unsigned short* vtb = vt + (size_t)(b * 4 + hv) * 64 * 2048;

  bf16x8 qf[4];
#pragma unroll
  for (int m = 0; m < 4; ++m)
    qf[m] = *(const bf16x8*)(qn + (tok0 + qglob) * 1024 + h * 64 + m * 16 + hi * 8);

  f32x16 oacc[2];
#pragma unroll
  for (int db = 0; db < 2; ++db)
#pragma unroll
    for (int r = 0; r < 16; ++r) oacc[db][r] = 0.f;
  float mrun = -INFINITY, lrun = 0.f;

  const int nt = qx * 2 + 2;

  auto stage = [&](int T, int buf) {
    unsigned short* KsB = SMEM + buf * 8192;
    unsigned short* VtB = KsB + 4096;
    const int kk0 = T * 64;
#pragma unroll
    for (int c = 0; c < 2; ++c) {
      int i = wid * 2 + c;
      int row = i * 8 + (lane >> 3);
      int sc = ((lane & 7) * 16) ^ ((row & 7) << 4);
      g2l16((const char*)(kn + (tok0 + kk0 + row) * 256 + hv * 64) + sc, (char*)KsB + i * 1024);
      g2l16((const char*)(vtb + (size_t)row * 2048 + kk0) + sc, (char*)VtB + i * 1024);
    }
  };

  stage(0, 0);
  __syncthreads();

  int cur = 0;
  for (int t = 0; t < nt; ++t) {
    const int k0 = t * 64;
    if (t + 1 < nt) stage(t + 1, cur ^ 1);  // prefetch overlaps compute below

    if (k0 <= q0w + 31) {
      const unsigned short* KsB = SMEM + cur * 8192;
      const unsigned short* VtB = KsB + 4096;
      // ---- S^T[key][q] = K · Q^T ----
      f32x16 s[2];
#pragma unroll
      for (int kt = 0; kt < 2; ++kt) {
        f32x16 acc;
#pragma unroll
        for (int r = 0; r < 16; ++r) acc[r] = 0.f;
        const int krow = kt * 32 + l31;
        const char* kbase = (const char*)KsB + krow * 128;
        const int ksw = (krow & 7) << 4;
        __builtin_amdgcn_s_setprio(1);
#pragma unroll
        for (int m = 0; m < 4; ++m) {
          bf16x8 kf = *(const bf16x8*)(kbase + ((m * 32 + hi * 16) ^ ksw));
          acc = __builtin_amdgcn_mfma_f32_32x32x16_bf16(kf, qf[m], acc, 0, 0, 0);
        }
        __builtin_amdgcn_s_setprio(0);
        s[kt] = acc;
      }
      // ---- causal mask (near-diagonal tiles only) ----
      if (k0 + 63 > q0w) {
#pragma unroll
        for (int kt = 0; kt < 2; ++kt)
#pragma unroll
          for (int r = 0; r < 16; ++r) {
            int key = k0 + kt * 32 + (r & 3) + 8 * (r >> 2) + 4 * hi;
            if (key > qglob) s[kt][r] = -INFINITY;
          }
      }
      // ---- online softmax, per-lane scalar state, log2 domain, defer-max (T13) ----
      float red[16];
#pragma unroll
      for (int r = 0; r < 16; ++r) red[r] = fmaxf(s[0][r], s[1][r]);
#pragma unroll
      for (int r = 0; r < 8; ++r) red[r] = fmaxf(red[r], red[r + 8]);
#pragma unroll
      for (int r = 0; r < 4; ++r) red[r] = fmaxf(red[r], red[r + 4]);
      float mx = fmaxf(fmaxf(red[0], red[1]), fmaxf(red[2], red[3]));
      mx = fmaxf(mx, __shfl_xor(mx, 32));
      if (!__all(mx - mrun <= 8.0f)) {
        float mnew = fmaxf(mrun, mx);
        float fsc = exp2f(mrun - mnew);
        lrun *= fsc;
#pragma unroll
        for (int db = 0; db < 2; ++db)
#pragma unroll
          for (int r = 0; r < 16; ++r) oacc[db][r] *= fsc;
        mrun = mnew;
      }
#pragma unroll
      for (int kt = 0; kt < 2; ++kt)
#pragma unroll
        for (int r = 0; r < 16; ++r) s[kt][r] = exp2f(s[kt][r] - mrun);
      float sr[16];
#pragma unroll
      for (int r = 0; r < 16; ++r) sr[r] = s[0][r] + s[1][r];
#pragma unroll
      for (int r = 0; r < 8; ++r) sr[r] += sr[r + 8];
#pragma unroll
      for (int r = 0; r < 4; ++r) sr[r] += sr[r + 4];
      float ps = (sr[0] + sr[1]) + (sr[2] + sr[3]);
      ps += __shfl_xor(ps, 32);
      lrun += ps;
      // ---- P -> bf16 frags via cvt_pk + permlane32_swap (T12) ----
      i32x4 paw[4];
#pragma unroll
      for (int kt = 0; kt < 2; ++kt)
#pragma unroll
        for (int half = 0; half < 2; ++half) {
          int bs = half * 8;
          unsigned int a0 = cvtpk(s[kt][bs + 0], s[kt][bs + 1]);
          unsigned int a1 = cvtpk(s[kt][bs + 2], s[kt][bs + 3]);
          unsigned int b0 = cvtpk(s[kt][bs + 4], s[kt][bs + 5]);
          unsigned int b1 = cvtpk(s[kt][bs + 6], s[kt][bs + 7]);
          i32x2 r0 = __builtin_amdgcn_permlane32_swap((int)a0, (int)b0, false, false);
          i32x2 r1 = __builtin_amdgcn_permlane32_swap((int)a1, (int)b1, false, false);
          i32x4 w;
          w[0] = r0[0]; w[1] = r1[0]; w[2] = r0[1]; w[3] = r1[1];
          paw[kt * 2 + half] = w;
        }
      // ---- O^T += V^T · P^T ----
#pragma unroll
      for (int db = 0; db < 2; ++db) {
        const int vrow = db * 32 + l31;
        const char* vbase = (const char*)VtB + vrow * 128;
        const int vsw = (vrow & 7) << 4;
        __builtin_amdgcn_s_setprio(1);
#pragma unroll
        for (int ks = 0; ks < 4; ++ks) {
          bf16x8 vf = *(const bf16x8*)(vbase + ((ks * 32 + hi * 16) ^ vsw));
          oacc[db] = __builtin_amdgcn_mfma_f32_32x32x16_bf16(
              vf, __builtin_bit_cast(bf16x8, paw[ks]), oacc[db], 0, 0, 0);
        }
        __builtin_amdgcn_s_setprio(0);
      }
    }
    __syncthreads();  // drains prefetch (vmcnt) + protects buffer swap
    cur ^= 1;
  }

  // ---- epilogue: O^T -> per-wave LDS transpose -> coalesced row store ----
  const float inv = 1.0f / lrun;
  const int swl = (l31 & 7) << 4;
  char* obase = (char*)SMEM + wid * 4096;
#pragma unroll
  for (int db = 0; db < 2; ++db)
#pragma unroll
    for (int i = 0; i < 8; ++i) {
      int r = 2 * i;
      int dim = db * 32 + (r & 3) + 8 * (r >> 2) + 4 * hi;
      unsigned int w = (unsigned int)f2bf(oacc[db][r] * inv) |
                       ((unsigned int)f2bf(oacc[db][r + 1] * inv) << 16);
      *(unsigned int*)(obase + l31 * 128 + ((dim * 2) ^ swl)) = w;
    }
  __syncthreads();
#pragma unroll
  for (int it = 0; it < 4; ++it) {
    int cc = it * 2 + hi;
    i32x4 w = *(const i32x4*)(obase + l31 * 128 + ((cc * 16) ^ swl));
    *(i32x4*)(yb + (tok0 + q0w + l31) * 1024 + h * 64 + cc * 8) = w;
  }
}

// ---------------- launch ----------------
extern "C" void kernel_launch(void* const* d_in, const int* in_sizes, int n_in,
                              void* d_out, int out_size, void* d_ws, size_t ws_size,
                              hipStream_t stream) {
  (void)in_sizes; (void)n_in; (void)out_size; (void)ws_size;
  const float* x  = (const float*)d_in[0];
  const float* Wq = (const float*)d_in[1];
  const float* Wk = (const float*)d_in[2];
  const float* Wv = (const float*)d_in[3];
  const float* Wo = (const float*)d_in[4];
  const float* qg = (const float*)d_in[5];

  char* ws = (char*)d_ws;
  unsigned short* xb   = (unsigned short*)(ws);             // 16 MB  [8192][1024]
  unsigned short* wcat = (unsigned short*)(ws + 16777216);  // 3 MB   [1536][1024]
  unsigned short* wob  = (unsigned short*)(ws + 19922944);  // 2 MB   [1024][1024]
  unsigned short* qn   = (unsigned short*)(ws + 22020096);  // 16 MB  [8192][1024]
  unsigned short* kn   = (unsigned short*)(ws + 38797312);  // 4 MB   [8192][256]
  unsigned short* yb   = xb;                                // alias: xb dead after QKV GEMM
  unsigned short* qkv  = (unsigned short*)d_out;            // 24 MB scratch in d_out
  unsigned short* vt   = (unsigned short*)((char*)d_out + 25165824);  // 4 MB [16][64][2048]

  k_cvt<<<4096, 256, 0, stream>>>(x, xb, 8388608);
  k_cvt<<<512, 256, 0, stream>>>(Wq, wcat, 1048576);
  k_cvt<<<128, 256, 0, stream>>>(Wk, wcat + 1048576, 262144);
  k_cvt<<<128, 256, 0, stream>>>(Wv, wcat + 1310720, 262144);
  k_cvt<<<512, 256, 0, stream>>>(Wo, wob, 1048576);

  k_gemm8<256, unsigned short><<<dim3(32, 6), 512, 0, stream>>>(xb, wcat, qkv, 8192, 1536, 1024);
  k_normrope<<<512, 256, 0, stream>>>(qkv, qg, qn, kn);
  k_vt<<<dim3(32, 16), 256, 0, stream>>>(qkv, vt);
  k_attn2<<<1024, 256, 0, stream>>>(qn, kn, vt, yb);
  k_gemm8<128, float><<<dim3(64, 4), 512, 0, stream>>>(yb, wob, (float*)d_out, 8192, 1024, 1024);
}